// Round 12
// baseline (108.872 us; speedup 1.0000x reference)
//
#include <hip/hip_runtime.h>
#include <math.h>

// Problem constants (B, D, C) from the reference.
#define NB 4096
#define ND 3072
#define NC 10
#define NM 9          // C-1
#define WSTRIDE 3076  // ND+4: k-major LDS row stride (bank de-conflict, 16B-aligned)

static constexpr float kEps      = 0.1f;
static constexpr float kNumStab  = 1e-6f;
static constexpr float kAlpha    = 1.0f - (float)NC * kNumStab;  // 1 - C*num_stab
static constexpr float kInvSqrtC = 0.31622776601683794f;         // 1/sqrt(10)

// ---------------------------------------------------------------------------
// Single fused kernel. Block = 1024 threads = 16 waves, grid = 256 (1 block/CU).
// R10/R11 diagnosis: the 256 MB workspace poison sweeps L3 every iteration, so
// `data` comes from HBM — and the kernel fetched it at 512 GB/s (2 B/cyc/CU),
// i.e. almost nothing in flight (depth-2 prefetch collapsed at low VGPR).
// Fix: issue ALL 12 float4 data loads per thread up front (48 VGPR of the 128
// granted by __launch_bounds__(1024,4)). 192 KB/CU in flight hides HBM latency
// under the W staging + Gram phases; the main loop then runs on register data.
// ---------------------------------------------------------------------------
__global__ __launch_bounds__(1024, 4) void fused_kernel(
        const float* __restrict__ data, const float* __restrict__ W,
        float* __restrict__ out) {
    __shared__ float Wts[NC * WSTRIDE];  // 123040 B, k-major: Wts[k*WSTRIDE + d]
    __shared__ float Gs[112];            // 10x10 Gram (padded)
    __shared__ float pzs[16][24];        // per-wave partial z, 12-float stride/sample
    __shared__ float regs[16];

    const int tid  = threadIdx.x;
    const int lane = tid & 63;
    const int wv   = tid >> 6;           // 0..15
    const int q    = wv >> 1;            // pair id 0..7
    const int half = wv & 1;             // which D-half this wave covers

    const int s0 = blockIdx.x * 16 + q * 2;          // pair's 2 samples
    const float* __restrict__ r0 = data + (size_t)s0 * ND + half * (ND / 2);
    const float* __restrict__ r1 = r0 + ND;

    // Issue ALL data loads now — statically unrolled so x0/x1 live in registers
    // (12 float4 = 48 VGPR). They drain from HBM while we stage W and do Gram.
    float4 x0[6], x1[6];
    #pragma unroll
    for (int it = 0; it < 6; ++it) {
        x0[it] = reinterpret_cast<const float4*>(r0)[it * 64 + lane];
        x1[it] = reinterpret_cast<const float4*>(r1)[it * 64 + lane];
    }

    // Stage W -> LDS transposed. Coalesced float4 global reads (W is L2-hot);
    // scattered one-time scalar LDS writes, de-conflicted by WSTRIDE.
    {
        const float4* W4 = reinterpret_cast<const float4*>(W);
        #pragma unroll
        for (int i = 0; i < 8; ++i) {
            const int c = tid + i * 1024;
            if (c < (ND * NC) / 4) {
                const float4 w4 = W4[c];
                const float* wp = reinterpret_cast<const float*>(&w4);
                const int e0 = c * 4;
                #pragma unroll
                for (int j = 0; j < 4; ++j) {
                    const int e = e0 + j;
                    Wts[(e % NC) * WSTRIDE + (e / NC)] = wp[j];
                }
            }
        }
    }
    __syncthreads();

    // Per-block Gram, row-shared: wave j computes G[j][k] for k>=j, reading
    // row j once per chunk. 780 ds_read_b128/block. Runs while the data loads
    // are still in flight. Waves 10-15 fall through to the main loop.
    if (wv < NC) {
        const int gj = wv;
        float ga[NC];
        #pragma unroll
        for (int k = 0; k < NC; ++k) ga[k] = 0.0f;
        for (int c = 0; c < 12; ++c) {
            const float4 aj = *reinterpret_cast<const float4*>(
                &Wts[gj * WSTRIDE + c * 256 + lane * 4]);
            #pragma unroll
            for (int k = 0; k < NC; ++k) {
                if (k >= gj) {   // wave-uniform branch
                    const float4 bk = *reinterpret_cast<const float4*>(
                        &Wts[k * WSTRIDE + c * 256 + lane * 4]);
                    ga[k] += aj.x * bk.x + aj.y * bk.y + aj.z * bk.z + aj.w * bk.w;
                }
            }
        }
        #pragma unroll
        for (int k = 0; k < NC; ++k) {
            if (k >= gj) {
                float v = ga[k];
                #pragma unroll
                for (int off = 32; off > 0; off >>= 1) v += __shfl_xor(v, off, 64);
                if (lane == 0) { Gs[gj * NC + k] = v; Gs[k * NC + gj] = v; }
            }
        }
    }
    // No barrier here: the epilogue's Gs reads are ordered by the pzs barrier.

    float acc[2][NC];
    #pragma unroll
    for (int s = 0; s < 2; ++s)
        #pragma unroll
        for (int k = 0; k < NC; ++k) acc[s][k] = 0.0f;

    const int dbase0 = half * (ND / 2);
    #pragma unroll
    for (int it = 0; it < 6; ++it) {
        const int dbase = dbase0 + it * 256 + lane * 4;
        #pragma unroll
        for (int k = 0; k < NC; ++k) {
            const float4 wt = *reinterpret_cast<const float4*>(&Wts[k * WSTRIDE + dbase]);
            acc[0][k] = fmaf(x0[it].x, wt.x, acc[0][k]);
            acc[0][k] = fmaf(x0[it].y, wt.y, acc[0][k]);
            acc[0][k] = fmaf(x0[it].z, wt.z, acc[0][k]);
            acc[0][k] = fmaf(x0[it].w, wt.w, acc[0][k]);
            acc[1][k] = fmaf(x1[it].x, wt.x, acc[1][k]);
            acc[1][k] = fmaf(x1[it].y, wt.y, acc[1][k]);
            acc[1][k] = fmaf(x1[it].z, wt.z, acc[1][k]);
            acc[1][k] = fmaf(x1[it].w, wt.w, acc[1][k]);
        }
    }

    // In-wave butterfly: every lane ends with this wave's full D-half partial.
    #pragma unroll
    for (int s = 0; s < 2; ++s)
        #pragma unroll
        for (int k = 0; k < NC; ++k) {
            float v = acc[s][k];
            #pragma unroll
            for (int off = 32; off > 0; off >>= 1) v += __shfl_xor(v, off, 64);
            acc[s][k] = v;
        }

    // Lane 0 publishes the wave's partials (vectorized, static reg indexing).
    if (lane == 0) {
        float4* p = reinterpret_cast<float4*>(&pzs[wv][0]);
        p[0] = make_float4(acc[0][0], acc[0][1], acc[0][2], acc[0][3]);
        p[1] = make_float4(acc[0][4], acc[0][5], acc[0][6], acc[0][7]);
        p[2] = make_float4(acc[0][8], acc[0][9], 0.0f, 0.0f);
        p[3] = make_float4(acc[1][0], acc[1][1], acc[1][2], acc[1][3]);
        p[4] = make_float4(acc[1][4], acc[1][5], acc[1][6], acc[1][7]);
        p[5] = make_float4(acc[1][8], acc[1][9], 0.0f, 0.0f);
    }
    __syncthreads();

    // Analytic epilogue on the even wave of each pair: lane 0 -> sample s0,
    // lane 1 -> sample s0+1. z = sum of the two waves' D-half partials.
    if (half == 0 && lane < 2) {
        float z[NC];
        #pragma unroll
        for (int k = 0; k < NC; ++k)
            z[k] = pzs[wv][lane * 12 + k] + pzs[wv + 1][lane * 12 + k];

        float zm = z[0];
        #pragma unroll
        for (int k = 1; k < NC; ++k) zm = fmaxf(zm, z[k]);
        float e[NC], Zs = 0.0f;
        #pragma unroll
        for (int k = 0; k < NC; ++k) { e[k] = expf(z[k] - zm); Zs += e[k]; }
        const float inv = 1.0f / Zs;

        float sg[NC], p[NC], sq[NC], u[NC];
        #pragma unroll
        for (int k = 0; k < NC; ++k) {
            sg[k] = e[k] * inv;                 // softmax probs (sigma)
            p[k]  = kAlpha * sg[k] + kNumStab;  // stabilized probs
            sq[k] = sqrtf(p[k]);                // s
            u[k]  = sg[k] / sq[k];              // sigma / s
        }
        const float qd = 1.0f - sq[NM];

        // v = G*sigma, t = sigma^T G sigma
        float v[NC], t = 0.0f;
        #pragma unroll
        for (int k = 0; k < NC; ++k) {
            float a = 0.0f;
            #pragma unroll
            for (int j = 0; j < NC; ++j) a = fmaf(Gs[k * NC + j], sg[j], a);
            v[k] = a;
            t = fmaf(sg[k], a, t);
        }
        const float vM = v[NM], uM = u[NM];
        const float QMM = Gs[NC * NC - 1] - 2.0f * vM + t;

        float sumJ = 0.0f;
        #pragma unroll
        for (int i = 0; i < NM; ++i) {
            const float Qii = Gs[i * NC + i] - 2.0f * v[i] + t;
            const float QiM = Gs[i * NC + NM] - v[i] - vM + t;
            const float r = sq[i] / qd;
            sumJ += u[i] * u[i] * Qii
                  + 2.0f * u[i] * uM * r * QiM
                  + uM * uM * r * r * QMM;
        }
        const float jn = (kAlpha / qd) * sqrtf(fmaxf(sumJ, 0.0f));

        float ssum = 0.0f;
        #pragma unroll
        for (int k = 0; k < NC; ++k) ssum += sq[k];
        const float ac = fminf(1.0f, fmaxf(-1.0f, ssum * kInvSqrtC));
        const float delta = 2.0f * acosf(ac);

        float psum = 0.0f;
        #pragma unroll
        for (int k = 0; k < NM; ++k) psum += p[k];
        const float rho = (2.0f * qd - psum) / qd;

        const float a = jn - delta / (rho * kEps);
        regs[q * 2 + lane] = (a > 0.0f) ? a : expm1f(a);
    }
    __syncthreads();
    if (tid == 0) {
        float bs = 0.0f;
        #pragma unroll
        for (int i = 0; i < 16; ++i) bs += regs[i];
        atomicAdd(out, bs * (1.0f / (float)NB));
    }
}

extern "C" void kernel_launch(void* const* d_in, const int* in_sizes, int n_in,
                              void* d_out, int out_size, void* d_ws, size_t ws_size,
                              hipStream_t stream) {
    const float* data = (const float*)d_in[0];
    const float* W    = (const float*)d_in[1];
    float* out = (float*)d_out;

    // d_out is re-poisoned to 0xAA before every timed launch -> zero it ourselves.
    hipMemsetAsync(out, 0, sizeof(float), stream);
    fused_kernel<<<NB / 16, 1024, 0, stream>>>(data, W, out);
}